// Round 9
// baseline (5896.382 us; speedup 1.0000x reference)
//
#include <hip/hip_runtime.h>

// Per-channel LSTM (input_size=1) + per-channel Linear(H,1), fully fused.
// B=512, T=1024, C=64, H=128.
// Round 15: packed-FP32 activation math (issue-cycle reduction under H2).
//   R14 verdict: cross-block skew = perfect null (5484 vs 5504) -> H2
//   confirmed: gfx950 SIMD serializes MFMA+VALU issue; MfmaUtil+VALUBusy
//   ==100% is an identity. Wall = total issue cycles. Only lever left:
//   fewer issue cycles. Trans (5 exp2 + 2 rcp per cell) is the algebraic
//   minimum; MFMA fixed; the regular-VALU slice (~16 ops/cell) halves via
//   v_pk_{fma,mul,add}_f32 (full-rate packed f32, gfx90a+), which LLVM
//   selects from <2 x float> arithmetic. Activation rows processed in
//   pairs as float2; acc-init vectorized to float4 (2 pk_fma per gate).
//   Precision: packed f32 is IEEE-identical to scalar; f16 stores keep
//   scalar RNE casts -> absmax unchanged (4.9e-4).
//   TRIPWIRES: VGPR<=128, WRITE_SIZE~1024KB, LDS=32768 exactly.

typedef _Float16 half8  __attribute__((ext_vector_type(8)));
typedef _Float16 half2v __attribute__((ext_vector_type(2)));
typedef float    floatx4 __attribute__((ext_vector_type(4)));
typedef float    floatx2 __attribute__((ext_vector_type(2)));

template <int N> struct ic_t { static constexpr int value = N; };

#define LOG2E 1.44269504088896340736f

__global__ __launch_bounds__(512, 2) void lstm_fused(
    const float* __restrict__ x,    // [B,T,C]
    const float* __restrict__ Wih,  // [C,4H]
    const float* __restrict__ Whh,  // [C,4H,H]
    const float* __restrict__ bih,  // [C,4H]
    const float* __restrict__ bhh,  // [C,4H]
    const float* __restrict__ Wfc,  // [C,H]
    const float* __restrict__ bfc,  // [C]
    float* __restrict__ out)        // [B,C]
{
    constexpr int T = 1024, C = 64, H = 128, G = 512;
    constexpr int TC = T * C;

    // Two h buffers: [4 rowtiles][4 ksteps][64 chunks][8 f16] = 16 KB each.
    // TOTAL LDS = 32768 exactly — do not add a single byte (2-block residency).
    __shared__ _Float16 hbuf[2][8192];

    const int bid = blockIdx.x;
    const int ch  = bid & 63;          // channel
    const int b0  = (bid >> 6) << 6;   // batch tile base: 0,64,...,448

    const int tid = threadIdx.x;
    const int w   = tid >> 6;          // wave 0..7 -> hidden slice [w*16, w*16+16)
    const int l   = tid & 63;
    const int q   = l >> 4;            // quad
    const int li  = l & 15;

    // ---- x addressing: uniform base pointer + per-lane 32-bit offset ----
    const float* xb = x + ch;
    const int rb0 = (b0 + q * 4) * TC;  // per-lane element offset base

    // x staging: two 4-reg buffers, each consumed one full phase after load.
    floatx4 xE, xO;
#pragma unroll
    for (int r = 0; r < 4; ++r) xE[r] = xb[rb0 + r * TC];          // t=0, rt0
#pragma unroll
    for (int r = 0; r < 4; ++r) xO[r] = xb[rb0 + (16 + r) * TC];   // t=0, rt1

    // ---- per-lane constants: packed W_ih+bias (f16), W_hh fragments ----
    half2v wbp[4];
    half8 Wf[4][4];
#pragma unroll
    for (int ct = 0; ct < 4; ++ct) {
        const float sc = (ct == 2) ? 2.0f * LOG2E : LOG2E;  // gate order i,f,g,o
        const int col = ct * H + w * 16 + li;
        wbp[ct][0] = (_Float16)(Wih[ch * G + col] * sc);
        wbp[ct][1] = (_Float16)((bih[ch * G + col] + bhh[ch * G + col]) * sc);
#pragma unroll
        for (int ks = 0; ks < 4; ++ks) {
            const float* wp = &Whh[((size_t)(ch * G + col)) * H + ks * 32 + q * 8];
            half8 hv;
#pragma unroll
            for (int j = 0; j < 8; ++j) hv[j] = (_Float16)(wp[j] * sc);
            Wf[ct][ks] = hv;
        }
    }

    // zero t=0 read buffer (h0 = 0)
    for (int i = tid; i < 8192; i += 512) hbuf[0][i] = (_Float16)0.0f;

    // cell state (fp32 registers): 4 rowtiles x 2 row-pairs (float2)
    floatx2 cst[4][2];
#pragma unroll
    for (int rt = 0; rt < 4; ++rt)
#pragma unroll
        for (int p = 0; p < 2; ++p) cst[rt][p] = (floatx2){0.0f, 0.0f};

    // ---- h layout with XOR bank swizzle ----
    // value (batch row m in tile, hidden hh): ks=hh>>5, qq=(hh&31)>>3, j=hh&7
    // chunk c = qq*16 + (m ^ (qq&3)); element = (rt*4+ks)*512 + c*8 + j
    const int ks_w = w >> 1;
    const int qq_w = ((w & 1) << 1) + (li >> 3);
    const int j_w  = li & 7;
    const int rxor = qq_w & 3;
    // write base: bits of (qq_w*16 + q*4), (r^rxor), ks_w*512, j_w are
    // disjoint -> addr(r) = K2 ^ (r*8), K2 = base ^ (rxor<<3).
    const int K2 = (ks_w * 512 + (qq_w * 16 + q * 4) * 8 + j_w) ^ (rxor << 3);
    // read: lane l wants chunk (qq=q, m=li) -> c = q*16 + (li ^ (q&3))
    const int rdoff = (q * 16 + (li ^ (q & 3))) * 8;

    __syncthreads();

    // ---- phase building blocks (rt strictly compile-time) ----
    auto mfma_rt = [&](auto rtc, floatx4 (&acc)[4], const _Float16* __restrict__ rb,
                       const floatx4& xq) {
        constexpr int rt = decltype(rtc)::value;
#pragma unroll
        for (int ct = 0; ct < 4; ++ct) {
            const float wi = (float)wbp[ct][0];
            const float bb = (float)wbp[ct][1];
            acc[ct] = xq * wi + bb;          // 2x v_pk_fma_f32
        }
#pragma unroll
        for (int ks = 0; ks < 4; ++ks) {
            const half8 a = *(const half8*)&rb[(rt * 4 + ks) * 512 + rdoff];
#pragma unroll
            for (int ct = 0; ct < 4; ++ct)
                acc[ct] = __builtin_amdgcn_mfma_f32_16x16x32_f16(a, Wf[ct][ks], acc[ct], 0, 0, 0);
        }
    };

    // one row-PAIR of activations in packed f32 (v_pk_*): rows 2P, 2P+1.
    // Math identical to R11's per-row scalar version (IEEE f32 throughout):
    //   sig(i)=1/Du, sig(f)=1/Dv, tanh(g)=(p-1)/Dp, sig(o)=1/Dw
    //   c' = [c*Du*Dp + (p-1)*Dv] * rcp(Du*Dv*Dp)
    //   h' = sig(o)*tanh(c') = (e-1) * rcp(Dw*(1+e)), e=exp2(clamped)
    auto act_pair = [&](auto rtc, auto pc, floatx4 (&acc)[4],
                        _Float16* __restrict__ wb) {
        constexpr int RT = decltype(rtc)::value;
        constexpr int P  = decltype(pc)::value;
        constexpr int R0 = 2 * P, R1 = 2 * P + 1;
        const floatx2 u2 = {__builtin_amdgcn_exp2f(-acc[0][R0]),
                            __builtin_amdgcn_exp2f(-acc[0][R1])};
        const floatx2 v2 = {__builtin_amdgcn_exp2f(-acc[1][R0]),
                            __builtin_amdgcn_exp2f(-acc[1][R1])};
        const floatx2 p2 = {__builtin_amdgcn_exp2f( acc[2][R0]),
                            __builtin_amdgcn_exp2f( acc[2][R1])};
        const floatx2 w2 = {__builtin_amdgcn_exp2f(-acc[3][R0]),
                            __builtin_amdgcn_exp2f(-acc[3][R1])};
        const floatx2 Du = 1.0f + u2, Dv = 1.0f + v2;
        const floatx2 Dp = 1.0f + p2, Dw = 1.0f + w2;
        const floatx2 DuDp = Du * Dp;
        const floatx2 A  = DuDp * Dv;
        const floatx2 Rv = {__builtin_amdgcn_rcpf(A[0]),
                            __builtin_amdgcn_rcpf(A[1])};
        const floatx2 cn = Rv * (cst[RT][P] * DuDp + (p2 - 1.0f) * Dv);
        cst[RT][P] = cn;
        const floatx2 tq = cn * (2.0f * LOG2E);
        const float ta = __builtin_amdgcn_fmed3f(tq[0], -29.0f, 29.0f);
        const float tb = __builtin_amdgcn_fmed3f(tq[1], -29.0f, 29.0f);
        const floatx2 e2 = {__builtin_amdgcn_exp2f(ta),
                            __builtin_amdgcn_exp2f(tb)};
        const floatx2 d2 = Dw * (1.0f + e2);
        const floatx2 R2 = {__builtin_amdgcn_rcpf(d2[0]),
                            __builtin_amdgcn_rcpf(d2[1])};
        const floatx2 h2 = e2 * R2 - R2;     // v_pk_fma_f32(e2, R2, -R2)
        wb[RT * 2048 + (K2 ^ (R0 * 8))] = (_Float16)h2[0];
        wb[RT * 2048 + (K2 ^ (R1 * 8))] = (_Float16)h2[1];
    };

    auto act_rt = [&](auto rtc, floatx4 (&acc)[4], _Float16* __restrict__ wb) {
        act_pair(rtc, ic_t<0>{}, acc, wb);
        act_pair(rtc, ic_t<1>{}, acc, wb);
    };

    auto load_x = [&](floatx4& xq, const float* base, int off) {
#pragma unroll
        for (int r = 0; r < 4; ++r) xq[r] = base[rb0 + off + r * TC];
    };

    auto step = [&](const _Float16* __restrict__ rb, _Float16* __restrict__ wb,
                    const float* xt, const float* xtn) {
        floatx4 accA[4], accB[4];
        // PRO
        mfma_rt(ic_t<0>{}, accA, rb, xE);
        load_x(xE, xt, 32 * TC);            // x(t, rt2)
        // P0
        mfma_rt(ic_t<1>{}, accB, rb, xO);
        load_x(xO, xt, 48 * TC);            // x(t, rt3)
        act_rt(ic_t<0>{}, accA, wb);
        // P1
        mfma_rt(ic_t<2>{}, accA, rb, xE);
        load_x(xE, xtn, 0);                 // x(t+1, rt0)
        act_rt(ic_t<1>{}, accB, wb);
        // P2
        mfma_rt(ic_t<3>{}, accB, rb, xO);
        load_x(xO, xtn, 16 * TC);           // x(t+1, rt1)
        act_rt(ic_t<2>{}, accA, wb);
        // P3
        act_rt(ic_t<3>{}, accB, wb);
        __syncthreads();
    };

    const float* xt = xb;
    for (int t = 0; t < T; t += 2) {
        const float* x1 = xt + C;                       // t+1 (t <= T-2)
        const float* x2 = (t + 2 < T) ? x1 + C : x1;    // t+2, clamped in-bounds
        step(hbuf[0], hbuf[1], xt, x1);
        step(hbuf[1], hbuf[0], x1, x2);
        xt = x2;
    }

    // ---- epilogue: out[b0+row, ch] = h_final . Wfc[ch] + bfc[ch] ----
    // T even -> final h is in hbuf[0]; last __syncthreads already done.
    if (tid < 64) {
        const int row = tid;
        const int rt = row >> 4, m = row & 15;
        float s = bfc[ch];
#pragma unroll
        for (int hh = 0; hh < H; ++hh) {
            const int ks = hh >> 5, qq = (hh & 31) >> 3, j = hh & 7;
            const int c = qq * 16 + (m ^ (qq & 3));
            s += (float)hbuf[0][(rt * 4 + ks) * 512 + c * 8 + j] * Wfc[ch * H + hh];
        }
        out[(size_t)(b0 + row) * C + ch] = s;
    }
}

extern "C" void kernel_launch(void* const* d_in, const int* in_sizes, int n_in,
                              void* d_out, int out_size, void* d_ws, size_t ws_size,
                              hipStream_t stream) {
    const float* x   = (const float*)d_in[0];
    const float* Wih = (const float*)d_in[1];
    const float* Whh = (const float*)d_in[2];
    const float* bih = (const float*)d_in[3];
    const float* bhh = (const float*)d_in[4];
    const float* Wfc = (const float*)d_in[5];
    const float* bfc = (const float*)d_in[6];
    float* out = (float*)d_out;

    lstm_fused<<<512, 512, 0, stream>>>(x, Wih, Whh, bih, bhh, Wfc, bfc, out);
}